// Round 2
// baseline (9242.107 us; speedup 1.0000x reference)
//
#include <hip/hip_runtime.h>

// MACE node message block, f32.
// N=10000 nodes, E=160000 edges, C=128, RB=8, HID=64.
// ws layout (floats):
//   [0 .. 1.28M)        s_up   (N,128)
//   [1.28M .. 5.12M)    v_up   (N,128,3)
//   [5.12M .. 15.36M)   msg    (N,1024)  = [s(256) | v(256*3)]
//   [15.36M .. +32768)  W4t    transposed/prescaled W_mlp4
// total 61.6 MB

#define N_NODES 10000
#define N_EDGES 160000

__device__ __forceinline__ float silu(float x) {
    return x / (1.0f + __expf(-x));
}

constexpr float INV_SQRT_C  = 0.08838834764831845f;   // 1/sqrt(128)
constexpr float INV_SQRT_RB = 0.35355339059327373f;   // 1/sqrt(8)
constexpr float INV_SQRT_H  = 0.125f;                 // 1/sqrt(64)
constexpr float OUT_SCALE   = 0.0625f * 0.0625f;      // 1/sqrt(256) * 1/AVG_NEIGH
constexpr float C000 = 0.7071067811865476f;           // sqrt(.5)
constexpr float C110 = 0.4082482904638631f;           // sqrt(.5)/sqrt(3)
constexpr float C011 = 0.7071067811865476f;           // sqrt(1.5)/sqrt(3) = sqrt(.5)
constexpr float C101 = 0.7071067811865476f;

// ---------------- K0: transpose + prescale W_mlp4 ----------------
// W4t[(c*4+a)*64 + k] = W4[k*512 + a*128 + c] / sqrt(64)
__global__ void k_w4t(const float* __restrict__ W4, float* __restrict__ W4t) {
    int o = blockIdx.x * 256 + threadIdx.x;   // 32768 total
    int c = o >> 8;
    int a = (o >> 6) & 3;
    int k = o & 63;
    W4t[o] = W4[k * 512 + a * 128 + c] * INV_SQRT_H;
}

// ---------------- K1: node up-projection ----------------
// s_up[n,d] = sum_c nf[n,c] * Wus[c,d] / sqrt(C)
// v_up[n,d,m] = sum_c nf[n,128+3c+m] * Wuv[c,d] / sqrt(C)
#define NPB 8
__global__ void k_node_up(const float* __restrict__ nf,
                          const float* __restrict__ Wus,
                          const float* __restrict__ Wuv,
                          float* __restrict__ s_up,
                          float* __restrict__ v_up) {
    __shared__ float lds[NPB][512];
    const int n0 = blockIdx.x * NPB;
    const int tid = threadIdx.x;  // 128 threads

    const float4* src = (const float4*)(nf + (size_t)n0 * 512);
    float4* dst = (float4*)(&lds[0][0]);
    #pragma unroll
    for (int i = 0; i < NPB; ++i) dst[tid + 128 * i] = src[tid + 128 * i];
    __syncthreads();

    const int d = tid;
    float acc_s[NPB];
    float acc_v[NPB][3];
    #pragma unroll
    for (int p = 0; p < NPB; ++p) {
        acc_s[p] = 0.f; acc_v[p][0] = 0.f; acc_v[p][1] = 0.f; acc_v[p][2] = 0.f;
    }
    for (int c = 0; c < 128; ++c) {
        float ws = Wus[c * 128 + d];
        float wv = Wuv[c * 128 + d];
        #pragma unroll
        for (int p = 0; p < NPB; ++p) {
            acc_s[p]    = fmaf(lds[p][c],             ws, acc_s[p]);
            acc_v[p][0] = fmaf(lds[p][128 + 3*c + 0], wv, acc_v[p][0]);
            acc_v[p][1] = fmaf(lds[p][128 + 3*c + 1], wv, acc_v[p][1]);
            acc_v[p][2] = fmaf(lds[p][128 + 3*c + 2], wv, acc_v[p][2]);
        }
    }
    #pragma unroll
    for (int p = 0; p < NPB; ++p) {
        int n = n0 + p;
        s_up[(size_t)n * 128 + d]         = acc_s[p]    * INV_SQRT_C;
        v_up[(size_t)n * 384 + 3*d + 0]   = acc_v[p][0] * INV_SQRT_C;
        v_up[(size_t)n * 384 + 3*d + 1]   = acc_v[p][1] * INV_SQRT_C;
        v_up[(size_t)n * 384 + 3*d + 2]   = acc_v[p][2] * INV_SQRT_C;
    }
}

// ---------------- K2: per-edge MLP + tensor-product messages + atomic scatter ----
// one thread = one edge; h arrays fully unrolled into registers;
// W reads are wave-uniform (same for all 64 edges in the wave) -> scalar loads.
__global__ __launch_bounds__(256) void k_edge(
    const float* __restrict__ edge_feats,
    const float* __restrict__ edge_attrs,
    const int*   __restrict__ edge_index,
    const float* __restrict__ W1,
    const float* __restrict__ W2,
    const float* __restrict__ W3,
    const float* __restrict__ W4t,
    const float* __restrict__ s_up,
    const float* __restrict__ v_up,
    float*       __restrict__ msg) {
    const int e = blockIdx.x * 256 + threadIdx.x;
    if (e >= N_EDGES) return;

    // edge inputs (coalesced)
    float4 ef0 = ((const float4*)edge_feats)[e * 2 + 0];
    float4 ef1 = ((const float4*)edge_feats)[e * 2 + 1];
    float ef[8] = {ef0.x, ef0.y, ef0.z, ef0.w, ef1.x, ef1.y, ef1.z, ef1.w};
    float4 ea = ((const float4*)edge_attrs)[e];
    const float y0 = ea.x, y10 = ea.y, y11 = ea.z, y12 = ea.w;
    const int snd = edge_index[e];
    const int rcv = edge_index[N_EDGES + e];

    // layer 1: 8 -> 64
    float h1[64];
    #pragma unroll
    for (int j = 0; j < 64; ++j) {
        float a0 = 0.f;
        #pragma unroll
        for (int k = 0; k < 8; ++k) a0 = fmaf(ef[k], W1[k * 64 + j], a0);
        h1[j] = silu(a0 * INV_SQRT_RB);
    }
    // layer 2: 64 -> 64
    float h2[64];
    #pragma unroll
    for (int j = 0; j < 64; ++j) h2[j] = 0.f;
    #pragma unroll
    for (int k = 0; k < 64; ++k) {
        float hk = h1[k];
        #pragma unroll
        for (int j = 0; j < 64; ++j) h2[j] = fmaf(hk, W2[k * 64 + j], h2[j]);
    }
    #pragma unroll
    for (int j = 0; j < 64; ++j) h2[j] = silu(h2[j] * INV_SQRT_H);
    // layer 3: 64 -> 64
    float h3[64];
    #pragma unroll
    for (int j = 0; j < 64; ++j) h3[j] = 0.f;
    #pragma unroll
    for (int k = 0; k < 64; ++k) {
        float hk = h2[k];
        #pragma unroll
        for (int j = 0; j < 64; ++j) h3[j] = fmaf(hk, W3[k * 64 + j], h3[j]);
    }
    #pragma unroll
    for (int j = 0; j < 64; ++j) h3[j] = silu(h3[j] * INV_SQRT_H);

    // layer 4 fused with tensor product + scatter, per channel c
    const float* __restrict__ sup = s_up + (size_t)snd * 128;
    const float* __restrict__ vup = v_up + (size_t)snd * 384;
    float* __restrict__ msr = msg + (size_t)rcv * 1024;

    for (int c = 0; c < 128; ++c) {
        // gathers first so they can issue under the FMA chain
        float se  = sup[c];
        float ve0 = vup[3 * c + 0];
        float ve1 = vup[3 * c + 1];
        float ve2 = vup[3 * c + 2];

        const float* w4c = W4t + c * 256;   // uniform across the wave
        float t0 = 0.f, t1 = 0.f, t2 = 0.f, t3 = 0.f;
        #pragma unroll
        for (int k = 0; k < 64; ++k) {
            float hk = h3[k];
            t0 = fmaf(hk, w4c[k],       t0);
            t1 = fmaf(hk, w4c[64 + k],  t1);
            t2 = fmaf(hk, w4c[128 + k], t2);
            t3 = fmaf(hk, w4c[192 + k], t3);
        }

        float m0a = C000 * t0 * se * y0;
        float dvy = ve0 * y10 + ve1 * y11 + ve2 * y12;
        float m0b = C110 * t3 * dvy;
        float c011t = C011 * t1 * se;
        float c101t = C101 * t2 * y0;

        atomicAdd(&msr[c],                 m0a);
        atomicAdd(&msr[128 + c],           m0b);
        atomicAdd(&msr[256 + 3 * c + 0],   c011t * y10);
        atomicAdd(&msr[256 + 3 * c + 1],   c011t * y11);
        atomicAdd(&msr[256 + 3 * c + 2],   c011t * y12);
        atomicAdd(&msr[640 + 3 * c + 0],   c101t * ve0);
        atomicAdd(&msr[640 + 3 * c + 1],   c101t * ve1);
        atomicAdd(&msr[640 + 3 * c + 2],   c101t * ve2);
    }
}

// ---------------- K3: final node linear ----------------
#define NPB3 8
__global__ void k_node_out(const float* __restrict__ msg,
                           const float* __restrict__ Wls,
                           const float* __restrict__ Wlv,
                           float* __restrict__ out) {
    __shared__ float lds[NPB3][1024];
    const int n0 = blockIdx.x * NPB3;
    const int tid = threadIdx.x;  // 128 threads

    const float4* src = (const float4*)(msg + (size_t)n0 * 1024);
    float4* dst = (float4*)(&lds[0][0]);
    #pragma unroll
    for (int i = 0; i < 2 * NPB3; ++i) dst[tid + 128 * i] = src[tid + 128 * i];
    __syncthreads();

    const int d = tid;
    float acc_s[NPB3];
    float acc_v[NPB3][3];
    #pragma unroll
    for (int p = 0; p < NPB3; ++p) {
        acc_s[p] = 0.f; acc_v[p][0] = 0.f; acc_v[p][1] = 0.f; acc_v[p][2] = 0.f;
    }
    for (int c = 0; c < 256; ++c) {
        float wls = Wls[c * 128 + d];
        float wlv = Wlv[c * 128 + d];
        #pragma unroll
        for (int p = 0; p < NPB3; ++p) {
            acc_s[p]    = fmaf(lds[p][c],               wls, acc_s[p]);
            acc_v[p][0] = fmaf(lds[p][256 + 3*c + 0],   wlv, acc_v[p][0]);
            acc_v[p][1] = fmaf(lds[p][256 + 3*c + 1],   wlv, acc_v[p][1]);
            acc_v[p][2] = fmaf(lds[p][256 + 3*c + 2],   wlv, acc_v[p][2]);
        }
    }
    #pragma unroll
    for (int p = 0; p < NPB3; ++p) {
        int n = n0 + p;
        out[(size_t)n * 512 + d]             = acc_s[p]    * OUT_SCALE;
        out[(size_t)n * 512 + 128 + 3*d + 0] = acc_v[p][0] * OUT_SCALE;
        out[(size_t)n * 512 + 128 + 3*d + 1] = acc_v[p][1] * OUT_SCALE;
        out[(size_t)n * 512 + 128 + 3*d + 2] = acc_v[p][2] * OUT_SCALE;
    }
}

extern "C" void kernel_launch(void* const* d_in, const int* in_sizes, int n_in,
                              void* d_out, int out_size, void* d_ws, size_t ws_size,
                              hipStream_t stream) {
    // input order per setup_inputs dict:
    // 0 node_attrs (unused), 1 node_feats, 2 edge_attrs, 3 edge_feats,
    // 4 edge_index, 5 W_up_s, 6 W_up_v, 7 W_mlp1, 8 W_mlp2, 9 W_mlp3,
    // 10 W_mlp4, 11 W_lin_s, 12 W_lin_v
    const float* node_feats = (const float*)d_in[1];
    const float* edge_attrs = (const float*)d_in[2];
    const float* edge_feats = (const float*)d_in[3];
    const int*   edge_index = (const int*)d_in[4];
    const float* W_up_s = (const float*)d_in[5];
    const float* W_up_v = (const float*)d_in[6];
    const float* W_mlp1 = (const float*)d_in[7];
    const float* W_mlp2 = (const float*)d_in[8];
    const float* W_mlp3 = (const float*)d_in[9];
    const float* W_mlp4 = (const float*)d_in[10];
    const float* W_lin_s = (const float*)d_in[11];
    const float* W_lin_v = (const float*)d_in[12];

    float* ws    = (float*)d_ws;
    float* s_up  = ws;                       // 1,280,000
    float* v_up  = ws + 1280000;             // 3,840,000
    float* msg   = ws + 5120000;             // 10,240,000
    float* W4t   = ws + 15360000;            // 32,768
    float* out_f = (float*)d_out;

    (void)hipMemsetAsync(msg, 0, (size_t)10240000 * sizeof(float), stream);
    k_w4t<<<128, 256, 0, stream>>>(W_mlp4, W4t);
    k_node_up<<<N_NODES / NPB, 128, 0, stream>>>(node_feats, W_up_s, W_up_v, s_up, v_up);
    k_edge<<<N_EDGES / 256, 256, 0, stream>>>(edge_feats, edge_attrs, edge_index,
                                              W_mlp1, W_mlp2, W_mlp3, W4t,
                                              s_up, v_up, msg);
    k_node_out<<<N_NODES / NPB3, 128, 0, stream>>>(msg, W_lin_s, W_lin_v, out_f);
}

// Round 4
// 3190.526 us; speedup vs baseline: 2.8967x; 2.8967x over previous
//
#include <hip/hip_runtime.h>

// MACE node message block, f32. CSR-gather, ws_size-adaptive chunking.
// N=10000 nodes, E=160000 edges, C=128, RB=8, HID=64.
//
// ws layout (float units from base):
//   [0 .. 1.28M)            s_up   (N,128)
//   [1.28M .. 5.12M)        v_up   (N,128,3)
//   [5.12M .. 15.36M)       msg    (N,1024); cnt/cursor ints live here pre-memset
//   [15.36M .. 15.392768M)  W4t
//   [15392768 .. +10001]    row    (int)
//   [15402772 .. +160000]   elist  (int)
//   [15562772 .. )          tpw    chunk buffer (float4 per (pos,c)), size adaptive
// mandatory: 62.25 MB; tpw full-E would be +327.7 MB (chunked if not available)

#define N_NODES 10000
#define N_EDGES 160000

#define S_UP_OFF   0u
#define V_UP_OFF   1280000u
#define MSG_OFF    5120000u
#define W4T_OFF    15360000u
#define ROW_OFF    15392768u
#define ELIST_OFF  15402772u
#define TPW_OFF    15562772u

__device__ __forceinline__ float silu(float x) {
    return x / (1.0f + __expf(-x));
}

constexpr float INV_SQRT_C  = 0.08838834764831845f;
constexpr float INV_SQRT_RB = 0.35355339059327373f;
constexpr float INV_SQRT_H  = 0.125f;
constexpr float OUT_SCALE   = 0.0625f * 0.0625f;      // 1/sqrt(256) / AVG_NEIGH
constexpr float C000 = 0.7071067811865476f;
constexpr float C110 = 0.4082482904638631f;
constexpr float C011 = 0.7071067811865476f;
constexpr float C101 = 0.7071067811865476f;

// ---------------- K0: transpose + prescale W_mlp4 ----------------
__global__ void k_w4t(const float* __restrict__ W4, float* __restrict__ W4t) {
    int o = blockIdx.x * 256 + threadIdx.x;   // 32768 total
    int c = o >> 8;
    int a = (o >> 6) & 3;
    int k = o & 63;
    W4t[o] = W4[k * 512 + a * 128 + c] * INV_SQRT_H;
}

// ---------------- K1: node up-projection ----------------
#define NPB 8
__global__ void k_node_up(const float* __restrict__ nf,
                          const float* __restrict__ Wus,
                          const float* __restrict__ Wuv,
                          float* __restrict__ s_up,
                          float* __restrict__ v_up) {
    __shared__ float lds[NPB][512];
    const int n0 = blockIdx.x * NPB;
    const int tid = threadIdx.x;  // 128 threads

    const float4* src = (const float4*)(nf + (size_t)n0 * 512);
    float4* dst = (float4*)(&lds[0][0]);
    #pragma unroll
    for (int i = 0; i < NPB; ++i) dst[tid + 128 * i] = src[tid + 128 * i];
    __syncthreads();

    const int d = tid;
    float acc_s[NPB];
    float acc_v[NPB][3];
    #pragma unroll
    for (int p = 0; p < NPB; ++p) {
        acc_s[p] = 0.f; acc_v[p][0] = 0.f; acc_v[p][1] = 0.f; acc_v[p][2] = 0.f;
    }
    for (int c = 0; c < 128; ++c) {
        float ws = Wus[c * 128 + d];
        float wv = Wuv[c * 128 + d];
        #pragma unroll
        for (int p = 0; p < NPB; ++p) {
            acc_s[p]    = fmaf(lds[p][c],             ws, acc_s[p]);
            acc_v[p][0] = fmaf(lds[p][128 + 3*c + 0], wv, acc_v[p][0]);
            acc_v[p][1] = fmaf(lds[p][128 + 3*c + 1], wv, acc_v[p][1]);
            acc_v[p][2] = fmaf(lds[p][128 + 3*c + 2], wv, acc_v[p][2]);
        }
    }
    #pragma unroll
    for (int p = 0; p < NPB; ++p) {
        int n = n0 + p;
        s_up[(size_t)n * 128 + d]         = acc_s[p]    * INV_SQRT_C;
        v_up[(size_t)n * 384 + 3*d + 0]   = acc_v[p][0] * INV_SQRT_C;
        v_up[(size_t)n * 384 + 3*d + 1]   = acc_v[p][1] * INV_SQRT_C;
        v_up[(size_t)n * 384 + 3*d + 2]   = acc_v[p][2] * INV_SQRT_C;
    }
}

// ---------------- CSR build ----------------
__global__ void k_hist(const int* __restrict__ ei, int* __restrict__ cnt) {
    int e = blockIdx.x * 256 + threadIdx.x;
    if (e < N_EDGES) atomicAdd(&cnt[ei[N_EDGES + e]], 1);
}

// single block, 256 threads, each covers 40 nodes
__global__ void k_scan(const int* __restrict__ cnt, int* __restrict__ row,
                       int* __restrict__ cursor) {
    __shared__ int part[256];
    const int t = threadIdx.x;
    const int base = t * 40;
    int s = 0;
    for (int i = 0; i < 40; ++i) {
        int idx = base + i;
        s += (idx < N_NODES) ? cnt[idx] : 0;
    }
    part[t] = s;
    __syncthreads();
    for (int off = 1; off < 256; off <<= 1) {
        int v = (t >= off) ? part[t - off] : 0;
        __syncthreads();
        part[t] += v;
        __syncthreads();
    }
    int run = part[t] - s;   // exclusive prefix
    for (int i = 0; i < 40; ++i) {
        int idx = base + i;
        if (idx < N_NODES) {
            row[idx] = run;
            cursor[idx] = run;
            run += cnt[idx];
        }
    }
    if (t == 255) row[N_NODES] = part[255];
}

__global__ void k_scatter(const int* __restrict__ ei, int* __restrict__ cursor,
                          int* __restrict__ elist) {
    int e = blockIdx.x * 256 + threadIdx.x;
    if (e < N_EDGES) {
        int r = ei[N_EDGES + e];
        int pos = atomicAdd(&cursor[r], 1);
        elist[pos] = e;
    }
}

// ---------------- K2: per-edge MLP -> tpw[pos-c0][c][4] ----------------
__global__ __launch_bounds__(256) void k_edge_mlp(
    const float* __restrict__ edge_feats,
    const float* __restrict__ W1,
    const float* __restrict__ W2,
    const float* __restrict__ W3,
    const float* __restrict__ W4t,
    const int*   __restrict__ elist,
    int c0, int ne,
    float4*      __restrict__ tpwv) {
    const int i = blockIdx.x * 256 + threadIdx.x;
    if (i >= ne) return;
    const int e = elist[c0 + i];

    float4 ef0 = ((const float4*)edge_feats)[e * 2 + 0];
    float4 ef1 = ((const float4*)edge_feats)[e * 2 + 1];
    float ef[8] = {ef0.x, ef0.y, ef0.z, ef0.w, ef1.x, ef1.y, ef1.z, ef1.w};

    // layer 1: 8 -> 64
    float h1[64];
    #pragma unroll
    for (int j = 0; j < 64; ++j) {
        float a0 = 0.f;
        #pragma unroll
        for (int k = 0; k < 8; ++k) a0 = fmaf(ef[k], W1[k * 64 + j], a0);
        h1[j] = silu(a0 * INV_SQRT_RB);
    }
    // layer 2: 64 -> 64
    float h2[64];
    #pragma unroll
    for (int j = 0; j < 64; ++j) h2[j] = 0.f;
    #pragma unroll
    for (int k = 0; k < 64; ++k) {
        float hk = h1[k];
        #pragma unroll
        for (int j = 0; j < 64; ++j) h2[j] = fmaf(hk, W2[k * 64 + j], h2[j]);
    }
    #pragma unroll
    for (int j = 0; j < 64; ++j) h2[j] = silu(h2[j] * INV_SQRT_H);
    // layer 3: 64 -> 64
    float h3[64];
    #pragma unroll
    for (int j = 0; j < 64; ++j) h3[j] = 0.f;
    #pragma unroll
    for (int k = 0; k < 64; ++k) {
        float hk = h2[k];
        #pragma unroll
        for (int j = 0; j < 64; ++j) h3[j] = fmaf(hk, W3[k * 64 + j], h3[j]);
    }
    #pragma unroll
    for (int j = 0; j < 64; ++j) h3[j] = silu(h3[j] * INV_SQRT_H);

    // layer 4: per channel c, 4 dots of 64; store float4 (edge-major)
    float4* __restrict__ tp = tpwv + (size_t)i * 128;
    for (int c = 0; c < 128; ++c) {
        const float* w4c = W4t + c * 256;   // wave-uniform -> scalar loads
        float t0 = 0.f, t1 = 0.f, t2 = 0.f, t3 = 0.f;
        #pragma unroll
        for (int k = 0; k < 64; ++k) {
            float hk = h3[k];
            t0 = fmaf(hk, w4c[k],       t0);
            t1 = fmaf(hk, w4c[64 + k],  t1);
            t2 = fmaf(hk, w4c[128 + k], t2);
            t3 = fmaf(hk, w4c[192 + k], t3);
        }
        tp[c] = make_float4(t0, t1, t2, t3);
    }
}

// ---------------- K3: CSR gather per node (msg +=, chunk-clipped) --------
__global__ __launch_bounds__(128) void k_gather(
    const int*    __restrict__ elist,
    const int*    __restrict__ row,
    const int*    __restrict__ ei,          // senders in ei[0..E)
    const float*  __restrict__ edge_attrs,
    const float4* __restrict__ tpwv,
    const float*  __restrict__ s_up,
    const float*  __restrict__ v_up,
    float*        __restrict__ msg,
    int c0, int c1) {
    const int nidx = blockIdx.x;
    const int c = threadIdx.x;      // 128 threads, one channel each
    int beg = row[nidx];
    int end = row[nidx + 1];
    if (beg < c0) beg = c0;
    if (end > c1) end = c1;
    if (beg >= end) return;

    float a0 = 0.f, a1 = 0.f, a2 = 0.f, a3 = 0.f,
          a4 = 0.f, a5 = 0.f, a6 = 0.f, a7 = 0.f;

    for (int i = beg; i < end; ++i) {
        const int e   = elist[i];
        const int snd = ei[e];
        const float4 ea = ((const float4*)edge_attrs)[e];
        const float y0 = ea.x, y10 = ea.y, y11 = ea.z, y12 = ea.w;

        const float4 t = tpwv[(size_t)(i - c0) * 128 + c];
        const float se  = s_up[(size_t)snd * 128 + c];
        const float ve0 = v_up[(size_t)snd * 384 + 3 * c + 0];
        const float ve1 = v_up[(size_t)snd * 384 + 3 * c + 1];
        const float ve2 = v_up[(size_t)snd * 384 + 3 * c + 2];

        a0 = fmaf(C000 * t.x * y0, se, a0);
        const float dvy = ve0 * y10 + ve1 * y11 + ve2 * y12;
        a1 = fmaf(C110 * t.w, dvy, a1);
        const float c011t = C011 * t.y * se;
        a2 = fmaf(c011t, y10, a2);
        a3 = fmaf(c011t, y11, a3);
        a4 = fmaf(c011t, y12, a4);
        const float c101t = C101 * t.z * y0;
        a5 = fmaf(c101t, ve0, a5);
        a6 = fmaf(c101t, ve1, a6);
        a7 = fmaf(c101t, ve2, a7);
    }

    float* m = msg + (size_t)nidx * 1024;
    m[c]               += a0;
    m[128 + c]         += a1;
    m[256 + 3 * c + 0] += a2;
    m[256 + 3 * c + 1] += a3;
    m[256 + 3 * c + 2] += a4;
    m[640 + 3 * c + 0] += a5;
    m[640 + 3 * c + 1] += a6;
    m[640 + 3 * c + 2] += a7;
}

// ---------------- K4: final node linear ----------------
#define NPB3 8
__global__ void k_node_out(const float* __restrict__ msg,
                           const float* __restrict__ Wls,
                           const float* __restrict__ Wlv,
                           float* __restrict__ out) {
    __shared__ float lds[NPB3][1024];
    const int n0 = blockIdx.x * NPB3;
    const int tid = threadIdx.x;  // 128 threads

    const float4* src = (const float4*)(msg + (size_t)n0 * 1024);
    float4* dst = (float4*)(&lds[0][0]);
    #pragma unroll
    for (int i = 0; i < 2 * NPB3; ++i) dst[tid + 128 * i] = src[tid + 128 * i];
    __syncthreads();

    const int d = tid;
    float acc_s[NPB3];
    float acc_v[NPB3][3];
    #pragma unroll
    for (int p = 0; p < NPB3; ++p) {
        acc_s[p] = 0.f; acc_v[p][0] = 0.f; acc_v[p][1] = 0.f; acc_v[p][2] = 0.f;
    }
    for (int c = 0; c < 256; ++c) {
        float wls = Wls[c * 128 + d];
        float wlv = Wlv[c * 128 + d];
        #pragma unroll
        for (int p = 0; p < NPB3; ++p) {
            acc_s[p]    = fmaf(lds[p][c],               wls, acc_s[p]);
            acc_v[p][0] = fmaf(lds[p][256 + 3*c + 0],   wlv, acc_v[p][0]);
            acc_v[p][1] = fmaf(lds[p][256 + 3*c + 1],   wlv, acc_v[p][1]);
            acc_v[p][2] = fmaf(lds[p][256 + 3*c + 2],   wlv, acc_v[p][2]);
        }
    }
    #pragma unroll
    for (int p = 0; p < NPB3; ++p) {
        int n = n0 + p;
        out[(size_t)n * 512 + d]             = acc_s[p]    * OUT_SCALE;
        out[(size_t)n * 512 + 128 + 3*d + 0] = acc_v[p][0] * OUT_SCALE;
        out[(size_t)n * 512 + 128 + 3*d + 1] = acc_v[p][1] * OUT_SCALE;
        out[(size_t)n * 512 + 128 + 3*d + 2] = acc_v[p][2] * OUT_SCALE;
    }
}

extern "C" void kernel_launch(void* const* d_in, const int* in_sizes, int n_in,
                              void* d_out, int out_size, void* d_ws, size_t ws_size,
                              hipStream_t stream) {
    const float* node_feats = (const float*)d_in[1];
    const float* edge_attrs = (const float*)d_in[2];
    const float* edge_feats = (const float*)d_in[3];
    const int*   edge_index = (const int*)d_in[4];
    const float* W_up_s = (const float*)d_in[5];
    const float* W_up_v = (const float*)d_in[6];
    const float* W_mlp1 = (const float*)d_in[7];
    const float* W_mlp2 = (const float*)d_in[8];
    const float* W_mlp3 = (const float*)d_in[9];
    const float* W_mlp4 = (const float*)d_in[10];
    const float* W_lin_s = (const float*)d_in[11];
    const float* W_lin_v = (const float*)d_in[12];

    float* ws     = (float*)d_ws;
    float* s_up   = ws + S_UP_OFF;
    float* v_up   = ws + V_UP_OFF;
    float* msg    = ws + MSG_OFF;
    float* W4t    = ws + W4T_OFF;
    int*   row    = (int*)(ws + ROW_OFF);
    int*   elist  = (int*)(ws + ELIST_OFF);
    float4* tpwv  = (float4*)(ws + TPW_OFF);
    // cnt/cursor live inside the msg region until it is memset
    int*   cnt    = (int*)msg;
    int*   cursor = cnt + N_NODES;
    float* out_f  = (float*)d_out;

    // adaptive chunking: tpw capacity from actual ws_size (deterministic)
    size_t total_f = ws_size / 4;
    size_t cap_f   = (total_f > TPW_OFF) ? (total_f - TPW_OFF) : 0;
    int chunkE = (int)((cap_f / 512 < (size_t)N_EDGES) ? cap_f / 512 : (size_t)N_EDGES);
    if (chunkE < 1) chunkE = 1;
    const int nch = (N_EDGES + chunkE - 1) / chunkE;

    (void)hipMemsetAsync(cnt, 0, N_NODES * sizeof(int), stream);
    k_w4t<<<128, 256, 0, stream>>>(W_mlp4, W4t);
    k_node_up<<<N_NODES / NPB, 128, 0, stream>>>(node_feats, W_up_s, W_up_v, s_up, v_up);
    k_hist<<<N_EDGES / 256, 256, 0, stream>>>(edge_index, cnt);
    k_scan<<<1, 256, 0, stream>>>(cnt, row, cursor);
    k_scatter<<<N_EDGES / 256, 256, 0, stream>>>(edge_index, cursor, elist);
    // msg zero-init (wipes cnt/cursor, no longer needed)
    (void)hipMemsetAsync(msg, 0, (size_t)10240000 * sizeof(float), stream);

    for (int ch = 0; ch < nch; ++ch) {
        const int c0 = ch * chunkE;
        const int c1 = (c0 + chunkE < N_EDGES) ? c0 + chunkE : N_EDGES;
        const int ne = c1 - c0;
        k_edge_mlp<<<(ne + 255) / 256, 256, 0, stream>>>(
            edge_feats, W_mlp1, W_mlp2, W_mlp3, W4t, elist, c0, ne, tpwv);
        k_gather<<<N_NODES, 128, 0, stream>>>(
            elist, row, edge_index, edge_attrs, tpwv, s_up, v_up, msg, c0, c1);
    }
    k_node_out<<<N_NODES / NPB3, 128, 0, stream>>>(msg, W_lin_s, W_lin_v, out_f);
}